// Round 3
// baseline (218.092 us; speedup 1.0000x reference)
//
#include <hip/hip_runtime.h>

// Problem constants
#define DIMX 256
#define NMX  32768   // N*M tokens per batch
#define TB   64      // tokens per workgroup

typedef short s16x8 __attribute__((ext_vector_type(8)));  // 8 bf16 in 4 VGPRs
typedef float f32x4 __attribute__((ext_vector_type(4)));

// ws layout (bytes): packed bf16 A-fragments per matrix, then fp32 Wkv temp
#define OFF_WQN   (0u)        // -Wq  (K=256,E=256) 128KB
#define OFF_WK    (131072u)   //  Wk                128KB
#define OFF_WKV   (262144u)   //  Wk@Wv             128KB
#define OFF_W1    (393216u)   //  W1  (K=256,E=128)  64KB
#define OFF_W2    (458752u)   //  W2  (K=128,E=256)  64KB
#define OFF_WO    (524288u)   //  Wo                128KB
#define OFF_KVF32 (655360u)   //  fp32 Wkv temp     256KB

__device__ __forceinline__ ushort f2bf(float f) {
  uint u = __builtin_bit_cast(uint, f);
  return (ushort)((u + 0x7FFFu + ((u >> 16) & 1u)) >> 16);  // RNE
}

// packed pair f32x2 -> 2xbf16 in one VALU op (gfx950 v_cvt_pk_bf16_f32, RNE)
__device__ __forceinline__ uint cvtpk(float lo, float hi) {
  uint r;
  asm("v_cvt_pk_bf16_f32 %0, %1, %2" : "=v"(r) : "v"(lo), "v"(hi));
  return r;
}
__device__ __forceinline__ float bf_lo(uint u) {
  return __builtin_bit_cast(float, u << 16);
}
__device__ __forceinline__ float bf_hi(uint u) {
  return __builtin_bit_cast(float, u & 0xffff0000u);
}

// K0: Wkv = Wk @ Wv in fp32 (256x256x256, trivial; Wk row is wave-uniform)
__global__ void wkv_kernel(const float* __restrict__ Wk, const float* __restrict__ Wv,
                           float* __restrict__ outw) {
  const int e = threadIdx.x, d = blockIdx.x;
  float acc = 0.f;
  #pragma unroll 8
  for (int m = 0; m < DIMX; ++m) acc += Wk[d * DIMX + m] * Wv[m * DIMX + e];
  outw[d * DIMX + e] = acc;
}

// K1: pack all weights into MFMA A-fragment order, bf16.
// A-frag for W(K x E) used as A = W^T: value[lane][j] = W[ks*32+(lane>>4)*8+j][r*16+(lane&15)]
// frag id = ks*(E/16)+r, stored at off + (frag*64+lane)*16 bytes.
__global__ void pack_kernel(const float* __restrict__ Wq, const float* __restrict__ Wk,
                            const float* __restrict__ Wkvf, const float* __restrict__ W1,
                            const float* __restrict__ W2, const float* __restrict__ Wo,
                            ushort* __restrict__ wsout) {
  const int fid = blockIdx.x, lane = threadIdx.x;  // 640 blocks x 64 threads
  const float* src; int Eout = 256; float sgn = 1.f; uint off; int local;
  if (fid < 128)      { src = Wq;   sgn = -1.f; off = OFF_WQN; local = fid;       }
  else if (fid < 256) { src = Wk;   off = OFF_WK;  local = fid - 128;             }
  else if (fid < 384) { src = Wkvf; off = OFF_WKV; local = fid - 256;             }
  else if (fid < 448) { src = W1;   Eout = 128; off = OFF_W1; local = fid - 384;  }
  else if (fid < 512) { src = W2;   off = OFF_W2;  local = fid - 448;             }
  else                { src = Wo;   off = OFF_WO;  local = fid - 512;             }
  const int R  = Eout >> 4;
  const int ks = local / R, r = local - ks * R;
  const int e  = r * 16 + (lane & 15);
  const int k0 = ks * 32 + (lane >> 4) * 8;
  union { uint4 u4; ushort us[8]; } o;
  #pragma unroll
  for (int j = 0; j < 8; ++j) o.us[j] = f2bf(sgn * src[(k0 + j) * Eout + e]);
  *(uint4*)((char*)wsout + off + (((uint)local * 64u + (uint)lane) * 16u)) = o.u4;
}

// Main fused kernel. WG = 64 tokens of one batch, 8 waves; wave w owns output
// rows [w*32, w*32+32) (rows [w*16,w*16+16) for the 128-wide hidden stage).
// LDS 48KB -> 3 WG/CU:
//   mainb 32KB [t][d]   pitch 512B : k -> attn -> x
//   auxb  16KB [t][d/2] pitch 256B : q-lo -> q-hi -> h
// XOR swizzle byte ^= (t&7)<<4; all LDS reads are single ds_read_b128,
// staging writes are ds_write_b128 (balanced banks).
#define MFMA16(A,B,C) __builtin_amdgcn_mfma_f32_16x16x32_bf16(A, B, C, 0, 0, 0)

__global__ __launch_bounds__(512, 6) void fused_main(
    const float* __restrict__ q, const float* __restrict__ kin,
    const float* __restrict__ pos, const int* __restrict__ mask,
    const float* __restrict__ b1, const float* __restrict__ b2,
    const float* __restrict__ bo, const ushort* __restrict__ wfr,
    float* __restrict__ out)
{
  __shared__ __align__(1024) ushort mainb[TB * DIMX];        // 32KB
  __shared__ __align__(1024) ushort auxb[TB * (DIMX / 2)];   // 16KB
  char* mb = (char*)mainb;
  char* ab = (char*)auxb;
  const char* wb = (const char*)wfr;

  const int tid = threadIdx.x;
  const int w = tid >> 6, l = tid & 63;
  const int c = l & 15, g = l >> 4;
  const int b  = blockIdx.x >> 9;           // 512 token-blocks per batch
  const int t0 = (blockIdx.x & 511) * TB;

  // B-fragment reads: lane supplies B[k = ks*32 + g*8 + j][t = tf*16 + c]
  auto ldBm = [&](int ks, int tf) -> s16x8 {  // main, 512B pitch, ks 0..7
    const int t = (tf << 4) + c;
    const int col = (ks << 6) + (g << 4);
    return *(const s16x8*)(mb + t * 512 + (col ^ ((t & 7) << 4)));
  };
  auto ldBa = [&](int ks, int tf) -> s16x8 {  // aux, 256B pitch, ks 0..3
    const int t = (tf << 4) + c;
    const int col = (ks << 6) + (g << 4);
    return *(const s16x8*)(ab + t * 256 + (col ^ ((t & 7) << 4)));
  };
  // A-fragment (weights) from packed global, 16B/lane
  auto ldA = [&](uint moff, int fi) -> s16x8 {
    return *(const s16x8*)(wb + moff + (((uint)fi << 6) | (uint)l) * 16u);
  };
  // write 4 consecutive-e bf16 values (packed lo,hi) at (e0, t)
  auto stM4 = [&](int e0, int t, uint lo, uint hi) {
    const int byte = t * 512 + (((uint)(e0 * 2)) ^ ((t & 7) << 4));
    *(uint2*)(mb + byte) = uint2{lo, hi};
  };
  auto stA4 = [&](int e0, int t, uint lo, uint hi) {
    const int byte = t * 256 + (((uint)(e0 * 2)) ^ ((t & 7) << 4));
    *(uint2*)(ab + byte) = uint2{lo, hi};
  };

  const size_t gbase = (size_t)b * DIMX * NMX + t0 + l;

  // stage k (full 256 d) -> mainb; wave w covers d in [w*32, w*32+32); t = l
  auto stage_k = [&]() {
    #pragma unroll
    for (int j4 = 0; j4 < 4; ++j4) {
      const int d0 = (w << 5) + (j4 << 3);
      uint pk[4];
      #pragma unroll
      for (int p = 0; p < 4; ++p) {
        const float v0 = kin[gbase + (size_t)(d0 + 2 * p) * NMX];
        const float v1 = kin[gbase + (size_t)(d0 + 2 * p + 1) * NMX];
        pk[p] = cvtpk(v0, v1);
      }
      const int byte = l * 512 + ((d0 * 2) ^ ((l & 7) << 4));
      *(uint4*)(mb + byte) = uint4{pk[0], pk[1], pk[2], pk[3]};
    }
  };
  // stage q half -> auxb; wave w covers d-within-half in [w*16, w*16+16)
  auto stage_qh = [&](int half) {
    #pragma unroll
    for (int j4 = 0; j4 < 2; ++j4) {
      const int dl = (w << 4) + (j4 << 3);      // d within half
      const int d  = (half << 7) + dl;
      uint pk[4];
      #pragma unroll
      for (int p = 0; p < 4; ++p) {
        const float v0 = q[gbase + (size_t)(d + 2 * p) * NMX];
        const float v1 = q[gbase + (size_t)(d + 2 * p + 1) * NMX];
        pk[p] = cvtpk(v0, v1);
      }
      const int byte = l * 256 + ((dl * 2) ^ ((l & 7) << 4));
      *(uint4*)(ab + byte) = uint4{pk[0], pk[1], pk[2], pk[3]};
    }
  };

  // ---- phase 1: stage k + q-lo ----
  stage_k();
  stage_qh(0);
  __syncthreads();

  // ---- phase 2a: av = Wkv^T k (full K), then pack to bf16 ----
  f32x4 av[2][4];
  #pragma unroll
  for (int ef = 0; ef < 2; ++ef)
    #pragma unroll
    for (int tf = 0; tf < 4; ++tf) av[ef][tf] = f32x4{0.f, 0.f, 0.f, 0.f};
  #pragma unroll 2
  for (int ks = 0; ks < 8; ++ks) {
    const s16x8 a0 = ldA(OFF_WKV, (ks << 4) + (w << 1));
    const s16x8 a1 = ldA(OFF_WKV, (ks << 4) + (w << 1) + 1);
    #pragma unroll
    for (int tf = 0; tf < 4; ++tf) {
      const s16x8 bf = ldBm(ks, tf);
      av[0][tf] = MFMA16(a0, bf, av[0][tf]);
      av[1][tf] = MFMA16(a1, bf, av[1][tf]);
    }
  }
  uint vbf[2][4][2];
  #pragma unroll
  for (int ef = 0; ef < 2; ++ef)
    #pragma unroll
    for (int tf = 0; tf < 4; ++tf) {
      vbf[ef][tf][0] = cvtpk(av[ef][tf][0], av[ef][tf][1]);
      vbf[ef][tf][1] = cvtpk(av[ef][tf][2], av[ef][tf][3]);
    }

  // ---- phase 2b: aa = Wk^T k (full K) ----
  f32x4 aa[2][4];
  #pragma unroll
  for (int ef = 0; ef < 2; ++ef)
    #pragma unroll
    for (int tf = 0; tf < 4; ++tf) aa[ef][tf] = f32x4{0.f, 0.f, 0.f, 0.f};
  #pragma unroll 2
  for (int ks = 0; ks < 8; ++ks) {
    const s16x8 a0 = ldA(OFF_WK, (ks << 4) + (w << 1));
    const s16x8 a1 = ldA(OFF_WK, (ks << 4) + (w << 1) + 1);
    #pragma unroll
    for (int tf = 0; tf < 4; ++tf) {
      const s16x8 bf = ldBm(ks, tf);
      aa[0][tf] = MFMA16(a0, bf, aa[0][tf]);
      aa[1][tf] = MFMA16(a1, bf, aa[1][tf]);
    }
  }

  // ---- phase 2c: aa += (-Wq)^T q-lo (global ks 0..3) ----
  #pragma unroll 2
  for (int ks = 0; ks < 4; ++ks) {
    const s16x8 a0 = ldA(OFF_WQN, (ks << 4) + (w << 1));
    const s16x8 a1 = ldA(OFF_WQN, (ks << 4) + (w << 1) + 1);
    #pragma unroll
    for (int tf = 0; tf < 4; ++tf) {
      const s16x8 bf = ldBa(ks, tf);
      aa[0][tf] = MFMA16(a0, bf, aa[0][tf]);
      aa[1][tf] = MFMA16(a1, bf, aa[1][tf]);
    }
  }
  __syncthreads();   // q-lo consumed by all waves

  // ---- phase 3: stage q-hi ----
  stage_qh(1);
  __syncthreads();

  // ---- phase 4a: aa += (-Wq)^T q-hi (global ks 4..7) ----
  #pragma unroll 2
  for (int ks = 4; ks < 8; ++ks) {
    const s16x8 a0 = ldA(OFF_WQN, (ks << 4) + (w << 1));
    const s16x8 a1 = ldA(OFF_WQN, (ks << 4) + (w << 1) + 1);
    #pragma unroll
    for (int tf = 0; tf < 4; ++tf) {
      const s16x8 bf = ldBa(ks - 4, tf);
      aa[0][tf] = MFMA16(a0, bf, aa[0][tf]);
      aa[1][tf] = MFMA16(a1, bf, aa[1][tf]);
    }
  }

  // ---- phase 4b: attn = aa + pos -> bf16 -> mainb; cache pos as bf16 ----
  uint posbf[2][4][2];
  #pragma unroll
  for (int tf = 0; tf < 4; ++tf) {
    const int t = (tf << 4) + c;
    const float* pp = pos + ((size_t)b * NMX + t0 + t) * DIMX;
    #pragma unroll
    for (int ef = 0; ef < 2; ++ef) {
      const int e0 = (w << 5) + (ef << 4) + (g << 2);
      const f32x4 p4 = *(const f32x4*)(pp + e0);
      posbf[ef][tf][0] = cvtpk(p4[0], p4[1]);
      posbf[ef][tf][1] = cvtpk(p4[2], p4[3]);
      const uint lo = cvtpk(aa[ef][tf][0] + p4[0], aa[ef][tf][1] + p4[1]);
      const uint hi = cvtpk(aa[ef][tf][2] + p4[2], aa[ef][tf][3] + p4[3]);
      stM4(e0, t, lo, hi);
    }
  }
  __syncthreads();   // attn tile complete (k dead, q-hi dead)

  // ---- phase 5: h = relu(W1^T attn + b1) -> auxb rows [w*16, w*16+16) ----
  f32x4 ah[4];
  #pragma unroll
  for (int tf = 0; tf < 4; ++tf) ah[tf] = f32x4{0.f, 0.f, 0.f, 0.f};
  #pragma unroll 2
  for (int ks = 0; ks < 8; ++ks) {
    const s16x8 a0 = ldA(OFF_W1, (ks << 3) + w);
    #pragma unroll
    for (int tf = 0; tf < 4; ++tf) {
      const s16x8 bf = ldBm(ks, tf);
      ah[tf] = MFMA16(a0, bf, ah[tf]);
    }
  }
  {
    const int e0 = (w << 4) + (g << 2);
    const f32x4 b1v = *(const f32x4*)(b1 + e0);
    #pragma unroll
    for (int tf = 0; tf < 4; ++tf) {
      const int t = (tf << 4) + c;
      const uint lo = cvtpk(fmaxf(ah[tf][0] + b1v[0], 0.f),
                            fmaxf(ah[tf][1] + b1v[1], 0.f));
      const uint hi = cvtpk(fmaxf(ah[tf][2] + b1v[2], 0.f),
                            fmaxf(ah[tf][3] + b1v[3], 0.f));
      stA4(e0, t, lo, hi);
    }
  }
  __syncthreads();   // h tile complete

  // ---- phase 6: a2 = W2^T h + b2; mask; sigmoid; x = (v+pos)*sig -> mainb ----
  f32x4 as[2][4];
  #pragma unroll
  for (int ef = 0; ef < 2; ++ef)
    #pragma unroll
    for (int tf = 0; tf < 4; ++tf) as[ef][tf] = f32x4{0.f, 0.f, 0.f, 0.f};
  #pragma unroll
  for (int ks = 0; ks < 4; ++ks) {
    const s16x8 a0 = ldA(OFF_W2, (ks << 4) + (w << 1));
    const s16x8 a1 = ldA(OFF_W2, (ks << 4) + (w << 1) + 1);
    #pragma unroll
    for (int tf = 0; tf < 4; ++tf) {
      const s16x8 bf = ldBa(ks, tf);
      as[0][tf] = MFMA16(a0, bf, as[0][tf]);
      as[1][tf] = MFMA16(a1, bf, as[1][tf]);
    }
  }
  #pragma unroll
  for (int tf = 0; tf < 4; ++tf) {
    const int t = (tf << 4) + c;
    const int mk = mask[(size_t)b * NMX + t0 + t];
    #pragma unroll
    for (int ef = 0; ef < 2; ++ef) {
      const int e0 = (w << 5) + (ef << 4) + (g << 2);
      const f32x4 b2v = *(const f32x4*)(b2 + e0);
      float xv[4];
      #pragma unroll
      for (int i = 0; i < 4; ++i) {
        float sv = as[ef][tf][i] + b2v[i];
        if (mk == 0) sv = -1e9f;
        const float sig = 1.f / (1.f + __expf(-sv));
        const uint pv = vbf[ef][tf][i >> 1];
        const uint pp = posbf[ef][tf][i >> 1];
        const float vv = (i & 1) ? bf_hi(pv) : bf_lo(pv);
        const float pf = (i & 1) ? bf_hi(pp) : bf_lo(pp);
        xv[i] = (vv + pf) * sig;
      }
      stM4(e0, t, cvtpk(xv[0], xv[1]), cvtpk(xv[2], xv[3]));
    }
  }
  __syncthreads();   // x tile complete

  // ---- phase 7: out = Wo^T x + bo -> (B, D, N, M) ----
  f32x4 ao[2][4];
  #pragma unroll
  for (int ef = 0; ef < 2; ++ef)
    #pragma unroll
    for (int tf = 0; tf < 4; ++tf) ao[ef][tf] = f32x4{0.f, 0.f, 0.f, 0.f};
  #pragma unroll 2
  for (int ks = 0; ks < 8; ++ks) {
    const s16x8 a0 = ldA(OFF_WO, (ks << 4) + (w << 1));
    const s16x8 a1 = ldA(OFF_WO, (ks << 4) + (w << 1) + 1);
    #pragma unroll
    for (int tf = 0; tf < 4; ++tf) {
      const s16x8 bf = ldBm(ks, tf);
      ao[0][tf] = MFMA16(a0, bf, ao[0][tf]);
      ao[1][tf] = MFMA16(a1, bf, ao[1][tf]);
    }
  }
  #pragma unroll
  for (int ef = 0; ef < 2; ++ef) {
    const int e0 = (w << 5) + (ef << 4) + (g << 2);
    const f32x4 bov = *(const f32x4*)(bo + e0);
    #pragma unroll
    for (int i = 0; i < 4; ++i) {
      float* ob = out + ((size_t)b * DIMX + e0 + i) * NMX + t0 + c;
      #pragma unroll
      for (int tf = 0; tf < 4; ++tf)
        ob[tf << 4] = ao[ef][tf][i] + bov[i];
    }
  }
}

extern "C" void kernel_launch(void* const* d_in, const int* in_sizes, int n_in,
                              void* d_out, int out_size, void* d_ws, size_t ws_size,
                              hipStream_t stream) {
  (void)in_sizes; (void)n_in; (void)out_size; (void)ws_size;
  const float* q   = (const float*)d_in[0];
  const float* k   = (const float*)d_in[1];
  const float* pos = (const float*)d_in[2];
  const int*   msk = (const int*)d_in[3];
  const float* Wq  = (const float*)d_in[4];
  const float* Wk  = (const float*)d_in[5];
  const float* Wv  = (const float*)d_in[6];
  const float* W1  = (const float*)d_in[7];
  const float* b1  = (const float*)d_in[8];
  const float* W2  = (const float*)d_in[9];
  const float* b2  = (const float*)d_in[10];
  const float* Wo  = (const float*)d_in[11];
  const float* bo  = (const float*)d_in[12];
  float* out = (float*)d_out;
  char* ws = (char*)d_ws;
  float*  wkvf = (float*)(ws + OFF_KVF32);
  ushort* wfr  = (ushort*)ws;

  wkv_kernel<<<dim3(256), dim3(256), 0, stream>>>(Wk, Wv, wkvf);
  pack_kernel<<<dim3(640), dim3(64), 0, stream>>>(Wq, Wk, wkvf, W1, W2, Wo, wfr);
  fused_main<<<dim3(2048), dim3(512), 0, stream>>>(q, k, pos, msk, b1, b2, bo, wfr, out);
}